// Round 5
// baseline (521.252 us; speedup 1.0000x reference)
//
#include <hip/hip_runtime.h>
#include <stdint.h>

// VectorQuantizer: z [65536,64] f32, codebook [1024,64] f32
// out = concat(q [B,C], z_q_st [B,D], loss [1]) all f32
#define NB    65536
#define NC    1024
#define ND    64
#define BR    32            // rows per block
#define NW    8             // waves per block (512 threads, 2 c per thread)

// Journal (measured):
//  R0 base scalar BR=32, 256thr x 4c:  vq_main 190us, VALUBusy 49%, occ 28% (3 w/SIMD, VGPR~168)
//  R1 BR=16+prefetch:                  266us (2x cbT instrs chip-wide) - BR must stay 32
//  R3 v_pk_fma_f32:                    218us, issue time UNCHANGED -> pk fp32 double-pumps on gfx950
//  R4 cbT reg double-buffer:           238us: +8 VGPR crossed 170 cliff -> 2 w/SIMD. VGPR<=170 is law.
//  R5 (this): 512thr x 2c (acc 128->64 VGPR) -> 4 w/SIMD @ cap 128, same work partitioning per c.

// ws layout (floats):
//  [0]              loss accumulator
//  [64 .. 1088)     wn2 (1024)
//  [2048 .. 67584)  cbT (64*1024), cbT[k*1024 + c] = cb[c*64 + k]

__global__ void vq_prep(const float* __restrict__ cb, float* __restrict__ ws) {
    int c = blockIdx.x * 64 + threadIdx.x;       // 0..1023
    float s = 0.f;
    #pragma unroll 8
    for (int k = 0; k < ND; ++k) {
        float v = cb[c * ND + k];
        ws[2048 + k * NC + c] = v;               // transpose (coalesced store)
        s = fmaf(v, v, s);
    }
    ws[64 + c] = s;                              // wn2
}

__device__ inline unsigned long long shfl_xor_u64(unsigned long long v, int m) {
    unsigned lo = (unsigned)v, hi = (unsigned)(v >> 32);
    lo = __shfl_xor(lo, m, 64);
    hi = __shfl_xor(hi, m, 64);
    return ((unsigned long long)hi << 32) | (unsigned long long)lo;
}

__global__ __launch_bounds__(512, 4) void vq_main(
    const float* __restrict__ z, const float* __restrict__ cb,
    const float* __restrict__ ws, float* __restrict__ q_out,
    float* __restrict__ zq_out, float* __restrict__ loss_acc)
{
    const int rb = blockIdx.x * BR;              // block's first row (uniform)
    const int t  = threadIdx.x;                  // c-pair id, 0..511
    const float* __restrict__ zb = z + (size_t)rb * ND;      // uniform base -> s_load
    const float2* __restrict__ cbT2 = (const float2*)(ws + 2048);
    const float2* __restrict__ wn22 = (const float2*)(ws + 64);

    __shared__ float part[512];
    __shared__ float zn2s[BR];
    __shared__ float sred[NW * BR];
    __shared__ unsigned long long kred[NW * BR];

    // ---- zn2 per row (order vs numpy irrelevant: uniform shift per row) ----
    {
        const float4* z4 = (const float4*)zb;    // 32 rows * 16 quads = 512
        float4 a = z4[t];
        part[t] = a.x*a.x + a.y*a.y + a.z*a.z + a.w*a.w;
    }
    __syncthreads();
    if (t < BR) {
        float s = 0.f;
        #pragma unroll
        for (int j = 0; j < 16; ++j) s += part[t * 16 + j];
        zn2s[t] = s;
    }
    __syncthreads();

    // ---- main K-loop: acc[r] = dot(z[rb+r,:], cb[c,:]) for c = 2t, 2t+1 ----
    float2 acc[BR];
    #pragma unroll
    for (int r = 0; r < BR; ++r) acc[r] = make_float2(0.f, 0.f);

    for (int kk = 0; kk < ND; kk += 4) {
        float2 c0 = cbT2[(size_t)(kk + 0) * 512 + t];
        float2 c1 = cbT2[(size_t)(kk + 1) * 512 + t];
        float2 c2 = cbT2[(size_t)(kk + 2) * 512 + t];
        float2 c3 = cbT2[(size_t)(kk + 3) * 512 + t];
        #pragma unroll
        for (int r = 0; r < BR; ++r) {
            // uniform (blockIdx-only) addresses -> scalar loads into SGPRs
            float z0 = zb[r * ND + kk + 0];
            float z1 = zb[r * ND + kk + 1];
            float z2 = zb[r * ND + kk + 2];
            float z3 = zb[r * ND + kk + 3];
            float2 a = acc[r];
            // same per-c accumulation order as the passing kernel (bit-identical d)
            a.x = fmaf(z0, c0.x, a.x); a.y = fmaf(z0, c0.y, a.y);
            a.x = fmaf(z1, c1.x, a.x); a.y = fmaf(z1, c1.y, a.y);
            a.x = fmaf(z2, c2.x, a.x); a.y = fmaf(z2, c2.y, a.y);
            a.x = fmaf(z3, c3.x, a.x); a.y = fmaf(z3, c3.y, a.y);
            acc[r] = a;
        }
    }

    // ---- epilogue stage 1: d -> q_unnorm, per-row wave reductions ----
    const int wv = t >> 6, lane = t & 63;
    float2 w2 = wn22[t];
    const int c0i = 2 * t;

    #pragma unroll
    for (int r = 0; r < BR; ++r) {
        float zn2r = zn2s[r];
        float2 a = acc[r];
        // exact reference association: (zn2 + wn2) - 2*dot
        float d0 = (zn2r + w2.x) - 2.f * a.x;
        float d1 = (zn2r + w2.y) - 2.f * a.y;
        float q0 = __builtin_amdgcn_rcpf(1.f + d0);
        float q1 = __builtin_amdgcn_rcpf(1.f + d1);
        acc[r] = make_float2(q0, q1);
        float ps = q0 + q1;
        // argmax with numpy tie-break (lowest c wins): d>=0 so bits are monotone
        unsigned long long k0 = ((unsigned long long)__float_as_uint(d0) << 32) | (unsigned)(1023 - (c0i + 0));
        unsigned long long k1 = ((unsigned long long)__float_as_uint(d1) << 32) | (unsigned)(1023 - (c0i + 1));
        unsigned long long key = k0 > k1 ? k0 : k1;
        #pragma unroll
        for (int m = 1; m < 64; m <<= 1) {
            ps += __shfl_xor(ps, m, 64);
            unsigned long long ok = shfl_xor_u64(key, m);
            key = key > ok ? key : ok;
        }
        if (lane == 0) { sred[wv * BR + r] = ps; kred[wv * BR + r] = key; }
    }
    __syncthreads();

    // ---- stage 2: combine waves, normalize, store q ----
    #pragma unroll
    for (int r = 0; r < BR; ++r) {
        float fs = ((sred[0 * BR + r] + sred[1 * BR + r]) + (sred[2 * BR + r] + sred[3 * BR + r]))
                 + ((sred[4 * BR + r] + sred[5 * BR + r]) + (sred[6 * BR + r] + sred[7 * BR + r]));
        float inv = __builtin_amdgcn_rcpf(fs);
        float2 a = acc[r];
        float2 o = make_float2(a.x * inv, a.y * inv);
        ((float2*)q_out)[(size_t)(rb + r) * (NC / 2) + t] = o;
    }

    // ---- z_q_st + loss ----
    float lsum = 0.f;
    #pragma unroll
    for (int i = 0; i < BR / NW; ++i) {
        int r = wv * (BR / NW) + i;
        unsigned long long k01 = kred[0 * BR + r] > kred[1 * BR + r] ? kred[0 * BR + r] : kred[1 * BR + r];
        unsigned long long k23 = kred[2 * BR + r] > kred[3 * BR + r] ? kred[2 * BR + r] : kred[3 * BR + r];
        unsigned long long k45 = kred[4 * BR + r] > kred[5 * BR + r] ? kred[4 * BR + r] : kred[5 * BR + r];
        unsigned long long k67 = kred[6 * BR + r] > kred[7 * BR + r] ? kred[6 * BR + r] : kred[7 * BR + r];
        unsigned long long ka = k01 > k23 ? k01 : k23;
        unsigned long long kb = k45 > k67 ? k45 : k67;
        unsigned long long km = ka > kb ? ka : kb;
        int bc = 1023 - (int)(unsigned)(km & 0xffffffffULL);
        float cv = cb[(size_t)bc * ND + lane];
        float zv = z[(size_t)(rb + r) * ND + lane];
        float t2 = cv - zv;                      // z_q - z
        zq_out[(size_t)(rb + r) * ND + lane] = zv + t2;  // z + sg(z_q - z)
        lsum = fmaf(t2, t2, lsum);
    }
    #pragma unroll
    for (int m = 1; m < 64; m <<= 1) lsum += __shfl_xor(lsum, m, 64);
    if (lane == 0) atomicAdd(loss_acc, lsum);
}

__global__ void vq_fin(const float* __restrict__ ws, float* __restrict__ loss_out) {
    if (threadIdx.x == 0) {
        float m = ws[0] / (float)((size_t)NB * ND);
        loss_out[0] = 0.25f * m + m;             // BETA*mean + mean
    }
}

extern "C" void kernel_launch(void* const* d_in, const int* in_sizes, int n_in,
                              void* d_out, int out_size, void* d_ws, size_t ws_size,
                              hipStream_t stream) {
    const float* z  = (const float*)d_in[0];
    const float* cb = (const float*)d_in[1];
    float* q_out    = (float*)d_out;
    float* zq_out   = q_out + (size_t)NB * NC;
    float* loss_out = zq_out + (size_t)NB * ND;
    float* ws       = (float*)d_ws;

    hipMemsetAsync(d_ws, 0, 4, stream);                      // zero loss accumulator
    vq_prep<<<NC / 64, 64, 0, stream>>>(cb, ws);
    vq_main<<<NB / BR, 512, 0, stream>>>(z, cb, ws, q_out, zq_out, ws);
    vq_fin<<<1, 64, 0, stream>>>(ws, loss_out);
}